// Round 6
// baseline (1839.587 us; speedup 1.0000x reference)
//
#include <hip/hip_runtime.h>

#define NQ 273
#define NQP 136   // q pairs 0..135 -> q=0..271; q=272 handled as singleton

typedef float f4 __attribute__((ext_vector_type(4)));
typedef float f2 __attribute__((ext_vector_type(2)));

// ---------------- compile-time GA tables (Cl(3,0,1) PGA, 16 blades) ----------------
struct GATab {
  int qi[NQ]; int qj[NQ]; int qk[NQ];
  float qs[NQ];
  int qgp[NQ];
  int qpath[NQ];
  int ngp, njp, nq;
};

constexpr int popc4(int m){ int c=0; for(int b=0;b<5;++b) c+=(m>>b)&1; return c; }
constexpr int swap_par(int a,int b){ int s=0; a>>=1; while(a){ s+=popc4(a&b); a>>=1; } return s&1; }

constexpr GATab make_tab(){
  GATab t{};
  int bladeOf[16]={}; int idxOf[16]={};
  { int p=0;
    for(int g=0; g<=4; ++g)
      for(int m=0; m<16; ++m)
        if(popc4(m)==g){ bladeOf[p]=m; idxOf[m]=p; ++p; }
  }
  int grade[16]={};
  for(int j=0;j<16;++j) grade[j]=popc4(bladeOf[j]);
  bool gpp[125]={}; bool jpp[125]={};
  for(int j=0;j<16;++j) for(int k=0;k<16;++k){
    int mj=bladeOf[j], mk=bladeOf[k];
    if(!(mj&mk&1)){ int i=idxOf[mj^mk]; gpp[(grade[i]*5+grade[j])*5+grade[k]]=true; }
    int cj=15^mj, ck=15^mk;
    if(!(cj&ck)){ int r=mj&mk; int i=idxOf[r]; jpp[(grade[i]*5+grade[j])*5+grade[k]]=true; }
  }
  int gpidx[125]={}; int jpidx[125]={};
  { int c=0; for(int u=0;u<125;++u){ gpidx[u] = gpp[u]? c++ : -1; } t.ngp=c; }
  { int c=0; for(int u=0;u<125;++u){ jpidx[u] = jpp[u]? c++ : -1; } t.njp=c; }
  int q=0;
  for(int j=0;j<16;++j) for(int k=0;k<16;++k){
    int mj=bladeOf[j], mk=bladeOf[k];
    if(!(mj&mk&1)){
      int i=idxOf[mj^mk];
      t.qi[q]=i; t.qj[q]=j; t.qk[q]=k;
      t.qs[q] = swap_par(mj,mk) ? -1.0f : 1.0f;
      t.qgp[q]=1;
      t.qpath[q]=gpidx[(grade[i]*5+grade[j])*5+grade[k]];
      ++q;
    }
  }
  for(int j=0;j<16;++j) for(int k=0;k<16;++k){
    int mj=bladeOf[j], mk=bladeOf[k];
    int cj=15^mj, ck=15^mk;
    if(!(cj&ck)){
      int r=mj&mk; int i=idxOf[r];
      int par = swap_par(mj,15^mj) ^ swap_par(mk,15^mk) ^ swap_par(cj,ck) ^ swap_par(r,15^r);
      t.qi[q]=i; t.qj[q]=j; t.qk[q]=k;
      t.qs[q] = par ? -1.0f : 1.0f;
      t.qgp[q]=0;
      t.qpath[q]=jpidx[(grade[i]*5+grade[j])*5+grade[k]];
      ++q;
    }
  }
  t.nq=q;
  return t;
}

constexpr GATab TAB = make_tab();
static_assert(TAB.nq == NQ, "nonzero count mismatch");
static_assert(TAB.ngp > 0 && TAB.njp > 0, "path counts");
constexpr int NGPC = TAB.ngp;
constexpr int NJPC = TAB.njp;
constexpr int GR[16] = {0,1,1,1,1,2,2,2,2,2,2,3,3,3,3,4};

__device__ __forceinline__ float rdlane(float v, int i){
  return __uint_as_float((unsigned)__builtin_amdgcn_readlane((int)__float_as_uint(v), i));
}
__device__ __forceinline__ f2 rdlane2(f2 v, int i){
  f2 r; r[0]=rdlane(v[0],i); r[1]=rdlane(v[1],i); return r;
}
__device__ __forceinline__ f2 fma2(float ws, f2 a, f2 c){
  f2 w; w[0]=ws; w[1]=ws;
  return __builtin_elementwise_fma(w, a, c);   // -> v_pk_fma_f32 (CDNA packed fp32)
}

// ---------------- prep kernels ----------------
// repack lin_weight (128,64,5) -> wrp[i][n][12]:
//   s in [0,5):  w1 grade s for output channel n      (o = n)
//   s in [5,10): w2 grade s-5 for output channel n+64 (o = 64+n)
//   s in [10,12): pad -> 48 B record, 3x dwordx4 per (i,n)
__global__ void prep_wrp(const float* __restrict__ linw, float* __restrict__ wrp){
  int t = blockIdx.x*blockDim.x + threadIdx.x;
  if(t < 64*64*12){
    int s = t % 12;
    int n = (t/12) & 63;
    int i = t/(12*64);
    float v = 0.f;
    if(s < 5)       v = linw[(n*64 + i)*5 + s];
    else if(s < 10) v = linw[((64+n)*64 + i)*5 + (s-5)];
    wrp[t] = v;
  }
}

// coef2[(q>>1)*128 + n*2 + (q&1)] = sign_q * w   (pair layout -> ds_read_b64 in main_k)
__global__ void prep_coef(const float* __restrict__ gpw, const float* __restrict__ jpw,
                          float* __restrict__ coef2){
  int n = threadIdx.x; // blockDim = 64, grid = 1
  #pragma unroll
  for(int q=0;q<NQ;++q){
    float w = TAB.qgp[q] ? gpw[n*NGPC + TAB.qpath[q]] : jpw[n*NJPC + TAB.qpath[q]];
    coef2[(q>>1)*128 + n*2 + (q&1)] = TAB.qs[q]*w;
  }
  coef2[136*128 + n*2 + 1] = 0.f;   // pad slot for odd NQ
}

// ---------------- main fused kernel ----------------
// 256-thread blocks (4 waves) -> 256-VGPR tier (no launch-bounds cap): zero spill.
// Each wave packs NB=2 batch elements into float2 registers -> v_pk_fma_f32:
//   - linear FMA issue halves; readlane pair shared by both elements.
//   - bilinear packed; coef read as ds_read_b64 pairs ([q/2][n][2] layout).
// coef (137*128 floats = 70144 B) in LDS -> 2 blocks/CU, 8 waves/CU.
__global__ __launch_bounds__(256)
void main_k(const float* __restrict__ x, const float* __restrict__ coef2,
            const float* __restrict__ wrp, float* __restrict__ out, int B){
  __shared__ float cl[(NQP+1)*128];   // 70144 B

  const int tid  = threadIdx.x;
  const int lane = tid & 63;
  const int wv   = tid >> 6;        // 0..3
  const int n    = lane;

  // ---- stage coef once per block: 4384 f4 / 256 thr = 18 chunks (guarded) ----
  {
    const f4* src = (const f4*)coef2;
    f4* dst = (f4*)cl;
    #pragma unroll
    for(int k=0;k<18;++k){
      int idx = tid + k*256;
      if(idx < (NQP+1)*32) dst[idx] = src[idx];
    }
  }
  __syncthreads();

  for(int base = blockIdx.x*8; base < B; base += gridDim.x*8){
    const int b0 = base + wv*2;
    const int b1 = b0 + 1;

    // ---- load 2 batch elements into packed float2 regs (lane = input channel) ----
    f2 xp[16];
    if(b0 < B){
      const f4* s0 = (const f4*)(x + ((long)b0*64 + lane)*16);
      #pragma unroll
      for(int r=0;r<4;++r){
        f4 a = __builtin_nontemporal_load(s0+r);
        #pragma unroll
        for(int c=0;c<4;++c){ xp[4*r+c][0]=a[c]; xp[4*r+c][1]=0.f; }
      }
    }
    if(b1 < B){
      const f4* s1 = (const f4*)(x + ((long)b1*64 + lane)*16);
      #pragma unroll
      for(int r=0;r<4;++r){
        f4 a = __builtin_nontemporal_load(s1+r);
        #pragma unroll
        for(int c=0;c<4;++c) xp[4*r+c][1]=a[c];
      }
    }

    // ---- linear phase (packed): y{1,2}p[v] = sum_i w{1,2}[g(v)] * x_pair[i][v] ----
    f2 y1p[16], y2p[16];
    #pragma unroll
    for(int v=0;v<16;++v){ y1p[v]=(f2)(0.f); y2p[v]=(f2)(0.f); }

    #pragma unroll 2
    for(int i=0;i<64;++i){
      const f4* wp = (const f4*)(wrp + (i*64 + n)*12);
      f4 wa = wp[0], wb = wp[1], wc = wp[2];
      float w1[5] = {wa[0],wa[1],wa[2],wa[3],wb[0]};
      float w2[5] = {wb[1],wb[2],wb[3],wc[0],wc[1]};
      #pragma unroll
      for(int v=0;v<16;++v){
        f2 sx = rdlane2(xp[v], i);   // (x[b0][i][v], x[b1][i][v]) wave-uniform
        y1p[v] = fma2(w1[GR[v]], sx, y1p[v]);
        y2p[v] = fma2(w2[GR[v]], sx, y2p[v]);
      }
    }

    // ---- bilinear phase (packed): acc[i] += coef[n,q]*y1[j]*y2[k]; coef via b64 pairs ----
    f2 accp[16];
    #pragma unroll
    for(int v=0;v<16;++v) accp[v]=y2p[v];

    const f2* clp = (const f2*)(cl + n*2);
    #pragma unroll
    for(int qp=0;qp<NQP;++qp){
      f2 c2 = clp[qp*64];           // (coef[2qp], coef[2qp+1]) for this lane
      constexpr int dummy = 0; (void)dummy;
      {
        const int q = 2*qp;
        accp[TAB.qi[q]] = fma2(c2[0], y1p[TAB.qj[q]]*y2p[TAB.qk[q]], accp[TAB.qi[q]]);
      }
      {
        const int q = 2*qp+1;
        accp[TAB.qi[q]] = fma2(c2[1], y1p[TAB.qj[q]]*y2p[TAB.qk[q]], accp[TAB.qi[q]]);
      }
    }
    { // singleton q = 272 (pair slot 136, even half; odd half is zero pad)
      const int q = 272;
      f2 c2 = clp[136*64];
      accp[TAB.qi[q]] = fma2(c2[0], y1p[TAB.qj[q]]*y2p[TAB.qk[q]], accp[TAB.qi[q]]);
    }

    // ---- store (unpack halves; streamed once -> nontemporal) ----
    if(b0 < B){
      f4* op = (f4*)(out + ((long)b0*64 + n)*16);
      #pragma unroll
      for(int r=0;r<4;++r){
        f4 o; o[0]=accp[4*r][0]; o[1]=accp[4*r+1][0]; o[2]=accp[4*r+2][0]; o[3]=accp[4*r+3][0];
        __builtin_nontemporal_store(o, op+r);
      }
    }
    if(b1 < B){
      f4* op = (f4*)(out + ((long)b1*64 + n)*16);
      #pragma unroll
      for(int r=0;r<4;++r){
        f4 o; o[0]=accp[4*r][1]; o[1]=accp[4*r+1][1]; o[2]=accp[4*r+2][1]; o[3]=accp[4*r+3][1];
        __builtin_nontemporal_store(o, op+r);
      }
    }
  }
}

extern "C" void kernel_launch(void* const* d_in, const int* in_sizes, int n_in,
                              void* d_out, int out_size, void* d_ws, size_t ws_size,
                              hipStream_t stream){
  const float* x    = (const float*)d_in[0];
  const float* gpw  = (const float*)d_in[1];
  const float* jpw  = (const float*)d_in[2];
  const float* linw = (const float*)d_in[3];
  float* outp = (float*)d_out;

  float* wrp   = (float*)d_ws;           // 64*64*12 floats = 192 KB
  float* coef2 = wrp + 64*64*12;         // 137*128 floats ≈ 70 KB

  int B = in_sizes[0] / (64*16);

  prep_wrp <<<192, 256, 0, stream>>>(linw, wrp);
  prep_coef<<<1,   64,  0, stream>>>(gpw, jpw, coef2);
  main_k   <<<512, 256, 0, stream>>>(x, coef2, wrp, outp, B);
}

// Round 7
// 818.070 us; speedup vs baseline: 2.2487x; 2.2487x over previous
//
#include <hip/hip_runtime.h>

#define NQ 273

typedef float f4 __attribute__((ext_vector_type(4)));

// ---------------- compile-time GA tables (Cl(3,0,1) PGA, 16 blades) ----------------
struct GATab {
  int qi[NQ]; int qj[NQ]; int qk[NQ];
  float qs[NQ];
  int qgp[NQ];
  int qpath[NQ];
  int ngp, njp, nq;
};

constexpr int popc4(int m){ int c=0; for(int b=0;b<5;++b) c+=(m>>b)&1; return c; }
constexpr int swap_par(int a,int b){ int s=0; a>>=1; while(a){ s+=popc4(a&b); a>>=1; } return s&1; }

constexpr GATab make_tab(){
  GATab t{};
  int bladeOf[16]={}; int idxOf[16]={};
  { int p=0;
    for(int g=0; g<=4; ++g)
      for(int m=0; m<16; ++m)
        if(popc4(m)==g){ bladeOf[p]=m; idxOf[m]=p; ++p; }
  }
  int grade[16]={};
  for(int j=0;j<16;++j) grade[j]=popc4(bladeOf[j]);
  bool gpp[125]={}; bool jpp[125]={};
  for(int j=0;j<16;++j) for(int k=0;k<16;++k){
    int mj=bladeOf[j], mk=bladeOf[k];
    if(!(mj&mk&1)){ int i=idxOf[mj^mk]; gpp[(grade[i]*5+grade[j])*5+grade[k]]=true; }
    int cj=15^mj, ck=15^mk;
    if(!(cj&ck)){ int r=mj&mk; int i=idxOf[r]; jpp[(grade[i]*5+grade[j])*5+grade[k]]=true; }
  }
  int gpidx[125]={}; int jpidx[125]={};
  { int c=0; for(int u=0;u<125;++u){ gpidx[u] = gpp[u]? c++ : -1; } t.ngp=c; }
  { int c=0; for(int u=0;u<125;++u){ jpidx[u] = jpp[u]? c++ : -1; } t.njp=c; }
  int q=0;
  for(int j=0;j<16;++j) for(int k=0;k<16;++k){
    int mj=bladeOf[j], mk=bladeOf[k];
    if(!(mj&mk&1)){
      int i=idxOf[mj^mk];
      t.qi[q]=i; t.qj[q]=j; t.qk[q]=k;
      t.qs[q] = swap_par(mj,mk) ? -1.0f : 1.0f;
      t.qgp[q]=1;
      t.qpath[q]=gpidx[(grade[i]*5+grade[j])*5+grade[k]];
      ++q;
    }
  }
  for(int j=0;j<16;++j) for(int k=0;k<16;++k){
    int mj=bladeOf[j], mk=bladeOf[k];
    int cj=15^mj, ck=15^mk;
    if(!(cj&ck)){
      int r=mj&mk; int i=idxOf[r];
      int par = swap_par(mj,15^mj) ^ swap_par(mk,15^mk) ^ swap_par(cj,ck) ^ swap_par(r,15^r);
      t.qi[q]=i; t.qj[q]=j; t.qk[q]=k;
      t.qs[q] = par ? -1.0f : 1.0f;
      t.qgp[q]=0;
      t.qpath[q]=jpidx[(grade[i]*5+grade[j])*5+grade[k]];
      ++q;
    }
  }
  t.nq=q;
  return t;
}

constexpr GATab TAB = make_tab();
static_assert(TAB.nq == NQ, "nonzero count mismatch");
static_assert(TAB.ngp > 0 && TAB.njp > 0, "path counts");
constexpr int NGPC = TAB.ngp;
constexpr int NJPC = TAB.njp;
constexpr int GR[16] = {0,1,1,1,1,2,2,2,2,2,2,3,3,3,3,4};

__device__ __forceinline__ float rdlane(float v, int i){
  return __uint_as_float((unsigned)__builtin_amdgcn_readlane((int)__float_as_uint(v), i));
}

// ---------------- prep kernels ----------------
// repack lin_weight (128,64,5) -> wrp[i][n][12]:
//   s in [0,5):  w1 grade s for output channel n      (o = n)
//   s in [5,10): w2 grade s-5 for output channel n+64 (o = 64+n)
//   s in [10,12): pad -> 48 B record, 3x dwordx4 per (i,n)
__global__ void prep_wrp(const float* __restrict__ linw, float* __restrict__ wrp){
  int t = blockIdx.x*blockDim.x + threadIdx.x;
  if(t < 64*64*12){
    int s = t % 12;
    int n = (t/12) & 63;
    int i = t/(12*64);
    float v = 0.f;
    if(s < 5)       v = linw[(n*64 + i)*5 + s];
    else if(s < 10) v = linw[((64+n)*64 + i)*5 + (s-5)];
    wrp[t] = v;
  }
}

// coef[q][n] = sign_q * (gp? gpw[n][path] : jpw[n][path]);  fully unrolled -> TAB folds
__global__ void prep_coef(const float* __restrict__ gpw, const float* __restrict__ jpw,
                          float* __restrict__ coef){
  int n = threadIdx.x; // blockDim = 64, grid = 1
  #pragma unroll
  for(int q=0;q<NQ;++q){
    float w = TAB.qgp[q] ? gpw[n*NGPC + TAB.qpath[q]] : jpw[n*NJPC + TAB.qpath[q]];
    coef[q*64 + n] = TAB.qs[q]*w;
  }
}

// ---------------- main fused kernel ----------------
// R5 structure, one change: __launch_bounds__(512, 1).
// With 512-thr blocks, min 1 wave/EU -> 2 waves/SIMD resident -> 256-VGPR cap
// (plain (512) defaulted to a 128 cap, which spilled ~18 floats/lane = ~300 MB
// of scratch writes per dispatch). Live set ~150-170 VGPRs -> now spill-free.
//  - coef (68 KB) in LDS, stride-1 per lane -> 0 bank conflicts (proven R5).
//  - x per-lane in 16 VGPRs; lane i broadcast via v_readlane (SGPR to FMA).
//  - weights stream from L2 (192 KB, resident; FETCH ~tiny, proven R5).
__global__ __launch_bounds__(512, 1)
void main_k(const float* __restrict__ x, const float* __restrict__ coef,
            const float* __restrict__ wrp, float* __restrict__ out, int B){
  __shared__ float cl[NQ*64];   // 68.25 KB

  const int tid  = threadIdx.x;
  const int lane = tid & 63;
  const int wv   = tid >> 6;        // 0..7
  const int n    = lane;

  // ---- stage coef once per block: 4368 f4 / 512 thr = 9 chunks ----
  {
    const f4* src = (const f4*)coef;
    f4* dst = (f4*)cl;
    #pragma unroll
    for(int k=0;k<9;++k){
      int idx = tid + k*512;
      if(idx < NQ*16) dst[idx] = src[idx];
    }
  }
  __syncthreads();

  for(int base = blockIdx.x*8; base < B; base += gridDim.x*8){
    const int bb = base + wv;

    // ---- load this wave's batch element into registers (lane = channel) ----
    f4 xr[4];
    if(bb < B){
      const f4* src = (const f4*)(x + ((long)bb*64 + lane)*16);
      #pragma unroll
      for(int r=0;r<4;++r) xr[r] = __builtin_nontemporal_load(src+r);
    }

    // ---- linear phase: y1[v] = sum_i w1[g(v)]*x[i][v], y2 likewise ----
    float y1[16], y2[16];
    #pragma unroll
    for(int v=0;v<16;++v){ y1[v]=0.f; y2[v]=0.f; }

    #pragma unroll 2
    for(int i=0;i<64;++i){
      const f4* wp = (const f4*)(wrp + (i*64 + n)*12);
      f4 wa = wp[0], wb = wp[1], wc = wp[2];
      float w1[5] = {wa[0],wa[1],wa[2],wa[3],wb[0]};
      float w2[5] = {wb[1],wb[2],wb[3],wc[0],wc[1]};
      #pragma unroll
      for(int v=0;v<16;++v){
        float xv = rdlane(xr[v>>2][v&3], i);   // x[bb][i][v], wave-uniform (SGPR)
        y1[v] = fmaf(w1[GR[v]], xv, y1[v]);
        y2[v] = fmaf(w2[GR[v]], xv, y2[v]);
      }
    }

    // ---- bilinear phase: acc[i] = y2[i] + sum_q coef[n,q]*y1[j_q]*y2[k_q] ----
    float acc[16];
    #pragma unroll
    for(int v=0;v<16;++v) acc[v]=y2[v];

    #pragma unroll
    for(int q=0;q<NQ;++q){
      float c = cl[q*64 + n];
      acc[TAB.qi[q]] = fmaf(c, y1[TAB.qj[q]]*y2[TAB.qk[q]], acc[TAB.qi[q]]);
    }

    // ---- store (streamed once -> nontemporal) ----
    if(bb < B){
      f4* op = (f4*)(out + ((long)bb*64 + n)*16);
      #pragma unroll
      for(int r=0;r<4;++r){
        f4 o; o[0]=acc[4*r]; o[1]=acc[4*r+1]; o[2]=acc[4*r+2]; o[3]=acc[4*r+3];
        __builtin_nontemporal_store(o, op+r);
      }
    }
  }
}

extern "C" void kernel_launch(void* const* d_in, const int* in_sizes, int n_in,
                              void* d_out, int out_size, void* d_ws, size_t ws_size,
                              hipStream_t stream){
  const float* x    = (const float*)d_in[0];
  const float* gpw  = (const float*)d_in[1];
  const float* jpw  = (const float*)d_in[2];
  const float* linw = (const float*)d_in[3];
  float* outp = (float*)d_out;

  float* wrp  = (float*)d_ws;          // 64*64*12 floats = 192 KB
  float* coef = wrp + 64*64*12;        // NQ*64 floats ≈ 68 KB

  int B = in_sizes[0] / (64*16);

  prep_wrp <<<192, 256, 0, stream>>>(linw, wrp);
  prep_coef<<<1,   64,  0, stream>>>(gpw, jpw, coef);
  main_k   <<<512, 512, 0, stream>>>(x, coef, wrp, outp, B);
}